// Round 2
// baseline (6427.467 us; speedup 1.0000x reference)
//
#include <hip/hip_runtime.h>
#include <hip/hip_bf16.h>

#define Hh 256
#define Ss 64
#define Tt 64
#define Bb 32
#define Vv 32000
#define NSLICE 8
#define SLW 32

typedef __attribute__((ext_vector_type(8))) __bf16 bf16x8;
typedef __attribute__((ext_vector_type(8))) unsigned short u16x8;
typedef __attribute__((ext_vector_type(4))) float f32x4;

__device__ __forceinline__ float bf2f(unsigned short u) {
    union { unsigned int i; float f; } v;
    v.i = ((unsigned int)u) << 16;
    return v.f;
}

// ---------------------------------------------------------------------------
// P1: annProj[row,:] = annotations[row,:] @ W1[H:2H,:] + b1. 4 rows/block so
// each weight element loaded once per 4 rows (was once per row): 2GB->0.5GB L2.
// ---------------------------------------------------------------------------
__global__ __launch_bounds__(256) void annproj_kernel(
    const float* __restrict__ ann, const float* __restrict__ W1,
    const float* __restrict__ b1, float* __restrict__ annP)
{
    int row0 = blockIdx.x * 4;
    int tid = threadIdx.x;
    __shared__ float sX[4][Hh];
    for (int idx = tid; idx < 4 * Hh; idx += 256)
        sX[idx >> 8][idx & 255] = ann[(size_t)row0 * Hh + idx];
    __syncthreads();
    const float* w = W1 + Hh * Hh;
    float b = b1[tid];
    float a0 = b, a1 = b, a2 = b, a3 = b;
#pragma unroll 2
    for (int i = 0; i < Hh; i++) {
        float wv = w[i * Hh + tid];
        a0 = fmaf(sX[0][i], wv, a0);
        a1 = fmaf(sX[1][i], wv, a1);
        a2 = fmaf(sX[2][i], wv, a2);
        a3 = fmaf(sX[3][i], wv, a3);
    }
    annP[(size_t)(row0 + 0) * Hh + tid] = a0;
    annP[(size_t)(row0 + 1) * Hh + tid] = a1;
    annP[(size_t)(row0 + 2) * Hh + tid] = a2;
    annP[(size_t)(row0 + 3) * Hh + tid] = a3;
}

// ---------------------------------------------------------------------------
// P2: embProj{Z,R,H} with fused biases, 4 token-rows per block.
// ---------------------------------------------------------------------------
__global__ __launch_bounds__(256) void embproj_kernel(
    const int* __restrict__ toks, const float* __restrict__ emb,
    const float* __restrict__ Wiz, const float* __restrict__ Wir,
    const float* __restrict__ Wih,
    const float* __restrict__ biz, const float* __restrict__ bir,
    const float* __restrict__ bih,
    const float* __restrict__ bhz, const float* __restrict__ bhr,
    float* __restrict__ eZ, float* __restrict__ eR, float* __restrict__ eH)
{
    int row0 = blockIdx.x * 4;
    int tid = threadIdx.x;
    __shared__ float sX[4][Hh];
#pragma unroll
    for (int r = 0; r < 4; r++)
        sX[r][tid] = emb[(size_t)toks[row0 + r] * Hh + tid];
    __syncthreads();
    const float* wz = Wiz + Hh * Hh;
    const float* wr = Wir + Hh * Hh;
    const float* wh = Wih + Hh * Hh;
    float bz = biz[tid] + bhz[tid];
    float br = bir[tid] + bhr[tid];
    float bh = bih[tid];
    float az[4], ar4[4], ah[4];
#pragma unroll
    for (int r = 0; r < 4; r++) { az[r] = bz; ar4[r] = br; ah[r] = bh; }
#pragma unroll 2
    for (int i = 0; i < Hh; i++) {
        int o = i * Hh + tid;
        float vz = wz[o], vr = wr[o], vh = wh[o];
#pragma unroll
        for (int r = 0; r < 4; r++) {
            float x = sX[r][i];
            az[r]  = fmaf(x, vz, az[r]);
            ar4[r] = fmaf(x, vr, ar4[r]);
            ah[r]  = fmaf(x, vh, ah[r]);
        }
    }
#pragma unroll
    for (int r = 0; r < 4; r++) {
        eZ[(size_t)(row0 + r) * Hh + tid] = az[r];
        eR[(size_t)(row0 + r) * Hh + tid] = ar4[r];
        eH[(size_t)(row0 + r) * Hh + tid] = ah[r];
    }
}

// ---------------------------------------------------------------------------
// P3: WoutT[n][k] = bf16(Wout[k][n])
// ---------------------------------------------------------------------------
__global__ __launch_bounds__(256) void transpose_wout_kernel(
    const float* __restrict__ Wout, __hip_bfloat16* __restrict__ BT)
{
    __shared__ float tile[64][65];
    int n0 = blockIdx.x * 64, k0 = blockIdx.y * 64;
    int tid = threadIdx.x;
    int c = tid & 63, rb = tid >> 6;
#pragma unroll
    for (int it = 0; it < 16; it++) {
        int kk = it * 4 + rb;
        tile[kk][c] = Wout[(size_t)(k0 + kk) * Vv + n0 + c];
    }
    __syncthreads();
#pragma unroll
    for (int it = 0; it < 16; it++) {
        int nn = it * 4 + rb;
        BT[(size_t)(n0 + nn) * Hh + k0 + c] = __float2bfloat16(tile[c][nn]);
    }
}

// ---------------------------------------------------------------------------
// P4a: pack W1_top COLUMN slices: W1cg[k][ic8][jj][8] = W1[ic8*8+d][k*32+jj]
// (slice k holds all 256 input rows x 32 output cols, bf16, 16KB per slice)
// ---------------------------------------------------------------------------
__global__ __launch_bounds__(256) void pack_w1col_kernel(
    const float* __restrict__ W1, __hip_bfloat16* __restrict__ W1cg)
{
    int k = blockIdx.x;
    int tid = threadIdx.x;
    int jj = tid & 31, icq = tid >> 5;
    for (int l = 0; l < 4; l++) {
        int ic8 = l * 8 + icq;
        __hip_bfloat16* dst = W1cg + (((size_t)k * 32 + ic8) * 32 + jj) * 8;
#pragma unroll
        for (int d = 0; d < 8; d++)
            dst[d] = __float2bfloat16(W1[(ic8 * 8 + d) * Hh + k * 32 + jj]);
    }
}

// ---------------------------------------------------------------------------
// P4b: pack 6 GRU matrices into ROW slices: RSg[m][k][c8][j][8] =
// Wm[k*32 + c8*8 + d][j].  m: 0=Wiz_top 1=Whz 2=Wih_top 3=Wir_top 4=Whr 5=Whh
// (slice k holds 32 input rows x all 256 cols, 16KB each, 96KB per slice)
// ---------------------------------------------------------------------------
__global__ __launch_bounds__(256) void pack_rs_kernel(
    const float* __restrict__ Wiz, const float* __restrict__ Whz,
    const float* __restrict__ Wih, const float* __restrict__ Wir,
    const float* __restrict__ Whr, const float* __restrict__ Whh,
    __hip_bfloat16* __restrict__ RSg)
{
    int k = blockIdx.x, m = blockIdx.y;
    int j = threadIdx.x;
    const float* src;
    switch (m) {
        case 0: src = Wiz; break;
        case 1: src = Whz; break;
        case 2: src = Wih; break;
        case 3: src = Wir; break;
        case 4: src = Whr; break;
        default: src = Whh; break;
    }
    for (int c8 = 0; c8 < 4; c8++) {
        __hip_bfloat16* dst = RSg + ((((size_t)m * NSLICE + k) * 4 + c8) * Hh + j) * 8;
#pragma unroll
        for (int d = 0; d < 8; d++)
            dst[d] = __float2bfloat16(src[(k * 32 + c8 * 8 + d) * Hh + j]);
    }
}

// ---------------------------------------------------------------------------
// P5: zero the sync counters (one-shot per launch; graph-replay safe)
// ---------------------------------------------------------------------------
__global__ void initcnt_kernel(unsigned int* __restrict__ cnt) {
    int i = blockIdx.x * 256 + threadIdx.x;
    if (i < Bb * Tt * 2) cnt[i] = 0u;
}

// ---------------------------------------------------------------------------
// K2: decoder scan, 256 blocks = 32 batch x 8 slices, cooperative launch.
// Each block keeps its 112KB weight slice in LDS for all 64 steps (zero
// weight re-streaming). Per step: 2 cross-block syncs through the coherent
// LLC (u-partials, gate-partials) with agent-scope atomics; h_new computed
// redundantly in every block. Buffers double-buffered by t-parity.
// ---------------------------------------------------------------------------
__global__ __launch_bounds__(512) void decoder_kernel(
    const float* __restrict__ ann, const float* __restrict__ h0,
    const __hip_bfloat16* __restrict__ W1cg, const __hip_bfloat16* __restrict__ RSg,
    const float* __restrict__ W2, const float* __restrict__ b2,
    const float* __restrict__ bhh,
    const float* __restrict__ annP,
    const float* __restrict__ eZ, const float* __restrict__ eR,
    const float* __restrict__ eH,
    float* __restrict__ uPart, float* __restrict__ gPart,
    unsigned int* __restrict__ cnt,
    __hip_bfloat16* __restrict__ hidBf, float* __restrict__ attOut)
{
    const int blk = blockIdx.x;
    const int b = blk >> 3;        // batch element
    const int k = blk & 7;         // slice id: owns j/i range [k*32, k*32+32)
    const int tid = threadIdx.x;
    const int j = tid & 255;       // column (two halves map to same j)
    const int st2 = tid >> 8;      // 0: streams {z, h_ctx}; 1: {r, hh}

    __shared__ __hip_bfloat16 lW1c[32][32][8];        // 16 KB col-slice of W1_top
    __shared__ __hip_bfloat16 lRS[6][4][Hh][8];       // 96 KB row-slices of GRU mats
    __shared__ float lAnnP[Ss][SLW + 1];              // 8.4 KB
    __shared__ float lAnnO[Ss][SLW + 1];              // 8.4 KB
    __shared__ __align__(16) float hLoc[Hh];
    __shared__ __align__(16) float ctxLoc[SLW];
    __shared__ float hpLoc[SLW];
    __shared__ float w2Loc[SLW];
    __shared__ float awLoc[Ss];
    __shared__ float sRedA[16][33];
    __shared__ float sRedB[8][Ss];
    __shared__ float sRedD[16][33];

    // ---- preload weight slices into LDS (once per launch) ----
    {
        u16x8* dW = (u16x8*)lW1c;
        const u16x8* sW = (const u16x8*)W1cg + (size_t)k * 1024;
        for (int idx = tid; idx < 1024; idx += 512) dW[idx] = sW[idx];
        u16x8* dR = (u16x8*)lRS;
        const u16x8* sR = (const u16x8*)RSg;
        for (int idx = tid; idx < 6144; idx += 512) {
            int m = idx >> 10, r = idx & 1023;
            dR[idx] = sR[(size_t)m * 8192 + (size_t)k * 1024 + r];
        }
        for (int idx = tid; idx < Ss * SLW; idx += 512) {
            int s = idx >> 5, ii = idx & 31;
            lAnnP[s][ii] = annP[((size_t)b * Ss + s) * Hh + k * SLW + ii];
            lAnnO[s][ii] = ann [((size_t)b * Ss + s) * Hh + k * SLW + ii];
        }
        if (tid < Hh)  hLoc[tid] = h0[b * Hh + tid];
        if (tid < SLW) w2Loc[tid] = W2[k * SLW + tid];
    }
    const float rbhh = (tid < Hh) ? bhh[j] : 0.f;
    const float b2s = b2[0];
    __syncthreads();

    const f32x4* h4full = (const f32x4*)hLoc;
    const f32x4* c4 = (const f32x4*)ctxLoc;
    const f32x4* h4sl = (const f32x4*)(hLoc + k * SLW);

    for (int t = 0; t < Tt; t++) {
        const int par = t & 1;
        const int rowt = b * Tt + t;

        // hoisted per-step embProj reads (hide under A..E)
        float ez = 0.f, er = 0.f, eh = 0.f;
        if (tid < Hh) {
            ez = eZ[(size_t)rowt * Hh + j];
            er = eR[(size_t)rowt * Hh + j];
            eh = eH[(size_t)rowt * Hh + j];
        }

        // --- A: hProj[jj in slice] = sum_i h[i]*W1top[i][jj], 16-way i-split
        {
            int q = tid >> 5, jj = tid & 31;
            float acc = 0.f;
#pragma unroll
            for (int c = 0; c < 2; c++) {
                int ic8 = q * 2 + c;
                u16x8 w = *(const u16x8*)&lW1c[ic8][jj][0];
                f32x4 ha = h4full[ic8 * 2], hb = h4full[ic8 * 2 + 1];
#pragma unroll
                for (int d = 0; d < 4; d++) {
                    acc = fmaf(bf2f(w[d]),     ha[d], acc);
                    acc = fmaf(bf2f(w[d + 4]), hb[d], acc);
                }
            }
            sRedA[q][jj] = acc;
        }
        __syncthreads();
        if (tid < SLW) {
            float s = 0.f;
#pragma unroll
            for (int q = 0; q < 16; q++) s += sRedA[q][tid];
            hpLoc[tid] = s;
        }
        __syncthreads();

        // --- B: u-partial over this slice's 32 columns
        {
            int s = tid & 63, g = tid >> 6;
            float pb = 0.f;
#pragma unroll
            for (int kk2 = 0; kk2 < 4; kk2++) {
                int jj = g * 4 + kk2;
                float v = hpLoc[jj] + lAnnP[s][jj];
                pb = fmaf(w2Loc[jj], fmaxf(v, 0.f), pb);
            }
            sRedB[g][s] = pb;
        }
        __syncthreads();
        if (tid < Ss) {
            float up = 0.f;
#pragma unroll
            for (int g = 0; g < 8; g++) up += sRedB[g][tid];
            __hip_atomic_store(&uPart[((size_t)(par * Bb + b) * NSLICE + k) * Ss + tid],
                               up, __ATOMIC_RELAXED, __HIP_MEMORY_SCOPE_AGENT);
        }
        __threadfence();
        __syncthreads();
        if (tid == 0)
            __hip_atomic_fetch_add(&cnt[rowt * 2 + 0], 1u,
                                   __ATOMIC_RELEASE, __HIP_MEMORY_SCOPE_AGENT);
        if (tid == 0) {
            while (__hip_atomic_load(&cnt[rowt * 2 + 0],
                   __ATOMIC_ACQUIRE, __HIP_MEMORY_SCOPE_AGENT) < NSLICE)
                __builtin_amdgcn_s_sleep(2);
        }
        __syncthreads();

        // --- C: full u, softmax (replicated in all 8 blocks of b)
        if (tid < Ss) {
            float u = b2s;
#pragma unroll
            for (int kk = 0; kk < NSLICE; kk++)
                u += __hip_atomic_load(
                    &uPart[((size_t)(par * Bb + b) * NSLICE + kk) * Ss + tid],
                    __ATOMIC_RELAXED, __HIP_MEMORY_SCOPE_AGENT);
            float m = u;
#pragma unroll
            for (int off = 32; off; off >>= 1) m = fmaxf(m, __shfl_xor(m, off));
            float e = __expf(u - m);
            float ssum = e;
#pragma unroll
            for (int off = 32; off; off >>= 1) ssum += __shfl_xor(ssum, off);
            float aw = e / ssum;
            awLoc[tid] = aw;
            if (k == 0) attOut[((size_t)b * Ss + tid) * Tt + t] = aw;
        }
        __syncthreads();

        // --- D: ctx[i in slice] = sum_s aw[s]*ann[b][s][i], 16-way s-split
        {
            int q = tid >> 5, ii = tid & 31;
            float pd = 0.f;
#pragma unroll
            for (int ss = 0; ss < 4; ss++) {
                int s = q * 4 + ss;
                pd = fmaf(awLoc[s], lAnnO[s][ii], pd);
            }
            sRedD[q][ii] = pd;
        }
        __syncthreads();
        if (tid < SLW) {
            float s = 0.f;
#pragma unroll
            for (int q = 0; q < 16; q++) s += sRedD[q][tid];
            ctxLoc[tid] = s;
        }
        __syncthreads();

        // --- E: gate partials over this slice's 32 input rows, all 256 cols.
        // st2=0: S0 = Wiz.ctx + Whz.h, S2 = Wih.ctx
        // st2=1: S1 = Wir.ctx + Whr.h, S3 = Whh.h
        {
            const int mb = st2 * 3;
            float a0 = 0.f, a1 = 0.f;
#pragma unroll
            for (int c8 = 0; c8 < 4; c8++) {
                u16x8 wx = *(const u16x8*)&lRS[mb + 0][c8][j][0];
                u16x8 wh = *(const u16x8*)&lRS[mb + 1][c8][j][0];
                u16x8 w3 = *(const u16x8*)&lRS[mb + 2][c8][j][0];
                f32x4 ca = c4[c8 * 2], cb = c4[c8 * 2 + 1];
                f32x4 ga = h4sl[c8 * 2], gb = h4sl[c8 * 2 + 1];
#pragma unroll
                for (int d = 0; d < 4; d++) {
                    a0 = fmaf(bf2f(wx[d]), ca[d], a0);
                    a0 = fmaf(bf2f(wh[d]), ga[d], a0);
                    a1 = fmaf(bf2f(w3[d]), st2 ? ga[d] : ca[d], a1);
                }
#pragma unroll
                for (int d = 0; d < 4; d++) {
                    a0 = fmaf(bf2f(wx[d + 4]), cb[d], a0);
                    a0 = fmaf(bf2f(wh[d + 4]), gb[d], a0);
                    a1 = fmaf(bf2f(w3[d + 4]), st2 ? gb[d] : cb[d], a1);
                }
            }
            size_t gb2 = ((size_t)(par * Bb + b) * NSLICE + k) * 4;
            __hip_atomic_store(&gPart[(gb2 + st2) * Hh + j], a0,
                               __ATOMIC_RELAXED, __HIP_MEMORY_SCOPE_AGENT);
            __hip_atomic_store(&gPart[(gb2 + 2 + st2) * Hh + j], a1,
                               __ATOMIC_RELAXED, __HIP_MEMORY_SCOPE_AGENT);
        }
        __threadfence();
        __syncthreads();
        if (tid == 0)
            __hip_atomic_fetch_add(&cnt[rowt * 2 + 1], 1u,
                                   __ATOMIC_RELEASE, __HIP_MEMORY_SCOPE_AGENT);
        if (tid == 0) {
            while (__hip_atomic_load(&cnt[rowt * 2 + 1],
                   __ATOMIC_ACQUIRE, __HIP_MEMORY_SCOPE_AGENT) < NSLICE)
                __builtin_amdgcn_s_sleep(2);
        }
        __syncthreads();

        // --- F: full gate sums, h update (replicated; identical fp order)
        if (tid < Hh) {
            float sz = 0.f, sr = 0.f, sh = 0.f, shh = 0.f;
#pragma unroll
            for (int kk = 0; kk < NSLICE; kk++) {
                size_t gb2 = ((size_t)(par * Bb + b) * NSLICE + kk) * 4;
                sz  += __hip_atomic_load(&gPart[(gb2 + 0) * Hh + j],
                        __ATOMIC_RELAXED, __HIP_MEMORY_SCOPE_AGENT);
                sr  += __hip_atomic_load(&gPart[(gb2 + 1) * Hh + j],
                        __ATOMIC_RELAXED, __HIP_MEMORY_SCOPE_AGENT);
                sh  += __hip_atomic_load(&gPart[(gb2 + 2) * Hh + j],
                        __ATOMIC_RELAXED, __HIP_MEMORY_SCOPE_AGENT);
                shh += __hip_atomic_load(&gPart[(gb2 + 3) * Hh + j],
                        __ATOMIC_RELAXED, __HIP_MEMORY_SCOPE_AGENT);
            }
            float z = 1.f / (1.f + __expf(-(ez + sz)));
            float r = 1.f / (1.f + __expf(-(er + sr)));
            float g = tanhf(eh + sh + r * (shh + rbhh));
            float hnew = (1.f - z) * g + z * hLoc[j];
            hLoc[j] = hnew;
            if (k == 0) hidBf[(size_t)rowt * Hh + j] = __float2bfloat16(hnew);
        }
        __syncthreads();
    }
}

// ---------------------------------------------------------------------------
// K3: output = hiddens(bf16) @ WoutT^T(bf16) + bout, fp32 out.
// ---------------------------------------------------------------------------
__global__ __launch_bounds__(256) void out_gemm_kernel(
    const __hip_bfloat16* __restrict__ A,   // (2048,256)
    const __hip_bfloat16* __restrict__ BT,  // (32000,256)
    const float* __restrict__ bout,
    float* __restrict__ C)                  // (2048,32000)
{
    int n0 = blockIdx.x * 128, m0 = blockIdx.y * 128;
    int tid = threadIdx.x;
    int w = tid >> 6, l = tid & 63;
    int wm = (w >> 1) * 64, wn = (w & 1) * 64;
    int quad = l >> 4, l15 = l & 15;

    const __hip_bfloat16* Arow = A + (size_t)(m0 + wm + l15) * Hh + quad * 8;
    const __hip_bfloat16* Brow = BT + (size_t)(n0 + wn + l15) * Hh + quad * 8;

    f32x4 acc[4][4] = {};
#pragma unroll
    for (int kk = 0; kk < 8; kk++) {
        bf16x8 af[4], bfv[4];
#pragma unroll
        for (int mi = 0; mi < 4; mi++)
            af[mi] = *(const bf16x8*)(Arow + mi * 16 * Hh + kk * 32);
#pragma unroll
        for (int ni = 0; ni < 4; ni++)
            bfv[ni] = *(const bf16x8*)(Brow + ni * 16 * Hh + kk * 32);
#pragma unroll
        for (int mi = 0; mi < 4; mi++)
#pragma unroll
            for (int ni = 0; ni < 4; ni++)
                acc[mi][ni] = __builtin_amdgcn_mfma_f32_16x16x32_bf16(
                    af[mi], bfv[ni], acc[mi][ni], 0, 0, 0);
    }
#pragma unroll
    for (int ni = 0; ni < 4; ni++) {
        int col = n0 + wn + ni * 16 + l15;
        float bo = bout[col];
#pragma unroll
        for (int mi = 0; mi < 4; mi++) {
            int rowb = m0 + wm + mi * 16 + quad * 4;
#pragma unroll
            for (int r = 0; r < 4; r++)
                C[(size_t)(rowb + r) * Vv + col] = acc[mi][ni][r] + bo;
        }
    }
}

// ---------------------------------------------------------------------------
extern "C" void kernel_launch(void* const* d_in, const int* in_sizes, int n_in,
                              void* d_out, int out_size, void* d_ws, size_t ws_size,
                              hipStream_t stream) {
    const int*   toks = (const int*)d_in[0];
    const float* ann  = (const float*)d_in[1];
    const float* h0   = (const float*)d_in[2];
    const float* emb  = (const float*)d_in[3];
    const float* W1   = (const float*)d_in[4];
    const float* b1   = (const float*)d_in[5];
    const float* W2   = (const float*)d_in[6];
    const float* b2   = (const float*)d_in[7];
    const float* Wiz  = (const float*)d_in[8];
    const float* biz  = (const float*)d_in[9];
    const float* Wir  = (const float*)d_in[10];
    const float* bir  = (const float*)d_in[11];
    const float* Wih  = (const float*)d_in[12];
    const float* bih  = (const float*)d_in[13];
    const float* Whz  = (const float*)d_in[14];
    const float* bhz  = (const float*)d_in[15];
    const float* Whr  = (const float*)d_in[16];
    const float* bhr  = (const float*)d_in[17];
    const float* Whh  = (const float*)d_in[18];
    const float* bhh  = (const float*)d_in[19];
    const float* Wout = (const float*)d_in[20];
    const float* bout = (const float*)d_in[21];

    float* out    = (float*)d_out;
    float* attOut = out + (size_t)Bb * Tt * Vv;

    float* ws   = (float*)d_ws;
    float* annP = ws;                                          // 524288 f32
    float* eZ   = ws + 524288;
    float* eR   = ws + 1048576;
    float* eH   = ws + 1572864;
    __hip_bfloat16* hidBf = (__hip_bfloat16*)(ws + 2097152);   // 524288 bf16
    __hip_bfloat16* WoutT = (__hip_bfloat16*)(ws + 2359296);   // 8192000 bf16
    __hip_bfloat16* W1cg  = (__hip_bfloat16*)(ws + 6455296);   // 65536 bf16
    __hip_bfloat16* RSg   = (__hip_bfloat16*)(ws + 6488064);   // 393216 bf16
    float* uPart = ws + 6684672;                               // 2*32*8*64 f32
    float* gPart = ws + 6717440;                               // 2*32*8*4*256 f32
    unsigned int* cnt = (unsigned int*)(ws + 7241728);         // 4096 u32

    annproj_kernel<<<dim3(Bb * Ss / 4), dim3(256), 0, stream>>>(ann, W1, b1, annP);
    embproj_kernel<<<dim3(Bb * Tt / 4), dim3(256), 0, stream>>>(
        toks, emb, Wiz, Wir, Wih, biz, bir, bih, bhz, bhr, eZ, eR, eH);
    transpose_wout_kernel<<<dim3(Vv / 64, Hh / 64), dim3(256), 0, stream>>>(Wout, WoutT);
    pack_w1col_kernel<<<dim3(NSLICE), dim3(256), 0, stream>>>(W1, W1cg);
    pack_rs_kernel<<<dim3(NSLICE, 6), dim3(256), 0, stream>>>(
        Wiz, Whz, Wih, Wir, Whr, Whh, RSg);
    initcnt_kernel<<<dim3(16), dim3(256), 0, stream>>>(cnt);

    void* dargs[] = { (void*)&ann, (void*)&h0, (void*)&W1cg, (void*)&RSg,
                      (void*)&W2, (void*)&b2, (void*)&bhh, (void*)&annP,
                      (void*)&eZ, (void*)&eR, (void*)&eH,
                      (void*)&uPart, (void*)&gPart, (void*)&cnt,
                      (void*)&hidBf, (void*)&attOut };
    hipLaunchCooperativeKernel((const void*)decoder_kernel,
                               dim3(Bb * NSLICE), dim3(512), dargs, 0, stream);

    out_gemm_kernel<<<dim3(Vv / 128, (Bb * Tt) / 128), dim3(256), 0, stream>>>(
        hidBf, WoutT, bout, out);
}

// Round 4
// 1134.157 us; speedup vs baseline: 5.6672x; 5.6672x over previous
//
#include <hip/hip_runtime.h>
#include <hip/hip_bf16.h>

#define Hh 256
#define Ss 64
#define Tt 64
#define Bb 32
#define Vv 32000

typedef __attribute__((ext_vector_type(8))) __bf16 bf16x8;
typedef __attribute__((ext_vector_type(8))) unsigned short u16x8;
typedef __attribute__((ext_vector_type(4))) float f32x4;

__device__ __forceinline__ float bf2f(unsigned short u) {
    union { unsigned int i; float f; } v;
    v.i = ((unsigned int)u) << 16;
    return v.f;
}

// ---------------------------------------------------------------------------
// P1: annprep — per encoder position s, precompute in one pass (8 rows/block):
//   annP[b,s,:] = ann @ W1_bot + b1          (attention key projection)
//   annZ[b,s,:] = ann @ Wiz_top              (z-gate context part)
//   annR[b,s,:] = ann @ Wir_top              (r-gate context part)
//   annH[b,s,:] = ann @ Wih_top              (h-gate context part)
// All stored bf16. This removes the 3 ctx matvecs (384 KB/step) from the
// decoder: Wi*_top @ ctx == sum_s aw[s] * ann*[s,:].
// ---------------------------------------------------------------------------
__global__ __launch_bounds__(256) void annprep_kernel(
    const float* __restrict__ ann, const float* __restrict__ W1,
    const float* __restrict__ b1,
    const float* __restrict__ Wiz, const float* __restrict__ Wir,
    const float* __restrict__ Wih,
    __hip_bfloat16* __restrict__ annPb, __hip_bfloat16* __restrict__ annZb,
    __hip_bfloat16* __restrict__ annRb, __hip_bfloat16* __restrict__ annHb)
{
    int row0 = blockIdx.x * 8;
    int j = threadIdx.x;
    __shared__ float sX[8][Hh];
    for (int idx = j; idx < 8 * Hh; idx += 256)
        sX[idx >> 8][idx & 255] = ann[(size_t)row0 * Hh + idx];
    __syncthreads();
    const float* w1b = W1 + Hh * Hh;   // annotations multiply bottom half of W1
    float aP[8], aZ[8], aR[8], aH[8];
    float b1j = b1[j];
#pragma unroll
    for (int r = 0; r < 8; r++) { aP[r] = b1j; aZ[r] = 0.f; aR[r] = 0.f; aH[r] = 0.f; }
#pragma unroll 2
    for (int i = 0; i < Hh; i++) {
        int o = i * Hh + j;
        float w1v = w1b[o], wzv = Wiz[o], wrv = Wir[o], whv = Wih[o];
#pragma unroll
        for (int r = 0; r < 8; r++) {
            float x = sX[r][i];
            aP[r] = fmaf(x, w1v, aP[r]);
            aZ[r] = fmaf(x, wzv, aZ[r]);
            aR[r] = fmaf(x, wrv, aR[r]);
            aH[r] = fmaf(x, whv, aH[r]);
        }
    }
#pragma unroll
    for (int r = 0; r < 8; r++) {
        size_t o = (size_t)(row0 + r) * Hh + j;
        annPb[o] = __float2bfloat16(aP[r]);
        annZb[o] = __float2bfloat16(aZ[r]);
        annRb[o] = __float2bfloat16(aR[r]);
        annHb[o] = __float2bfloat16(aH[r]);
    }
}

// ---------------------------------------------------------------------------
// P2: embProj{Z,R,H} with fused biases, 4 token-rows per block.
// ---------------------------------------------------------------------------
__global__ __launch_bounds__(256) void embproj_kernel(
    const int* __restrict__ toks, const float* __restrict__ emb,
    const float* __restrict__ Wiz, const float* __restrict__ Wir,
    const float* __restrict__ Wih,
    const float* __restrict__ biz, const float* __restrict__ bir,
    const float* __restrict__ bih,
    const float* __restrict__ bhz, const float* __restrict__ bhr,
    float* __restrict__ eZ, float* __restrict__ eR, float* __restrict__ eH)
{
    int row0 = blockIdx.x * 4;
    int tid = threadIdx.x;
    __shared__ float sX[4][Hh];
#pragma unroll
    for (int r = 0; r < 4; r++)
        sX[r][tid] = emb[(size_t)toks[row0 + r] * Hh + tid];
    __syncthreads();
    const float* wz = Wiz + Hh * Hh;
    const float* wr = Wir + Hh * Hh;
    const float* wh = Wih + Hh * Hh;
    float bz = biz[tid] + bhz[tid];
    float br = bir[tid] + bhr[tid];
    float bh = bih[tid];
    float az[4], ar4[4], ah[4];
#pragma unroll
    for (int r = 0; r < 4; r++) { az[r] = bz; ar4[r] = br; ah[r] = bh; }
#pragma unroll 2
    for (int i = 0; i < Hh; i++) {
        int o = i * Hh + tid;
        float vz = wz[o], vr = wr[o], vh = wh[o];
#pragma unroll
        for (int r = 0; r < 4; r++) {
            float x = sX[r][i];
            az[r]  = fmaf(x, vz, az[r]);
            ar4[r] = fmaf(x, vr, ar4[r]);
            ah[r]  = fmaf(x, vh, ah[r]);
        }
    }
#pragma unroll
    for (int r = 0; r < 4; r++) {
        eZ[(size_t)(row0 + r) * Hh + tid] = az[r];
        eR[(size_t)(row0 + r) * Hh + tid] = ar4[r];
        eH[(size_t)(row0 + r) * Hh + tid] = ah[r];
    }
}

// ---------------------------------------------------------------------------
// P3: WoutT[n][k] = bf16(Wout[k][n])
// ---------------------------------------------------------------------------
__global__ __launch_bounds__(256) void transpose_wout_kernel(
    const float* __restrict__ Wout, __hip_bfloat16* __restrict__ BT)
{
    __shared__ float tile[64][65];
    int n0 = blockIdx.x * 64, k0 = blockIdx.y * 64;
    int tid = threadIdx.x;
    int c = tid & 63, rb = tid >> 6;
#pragma unroll
    for (int it = 0; it < 16; it++) {
        int kk = it * 4 + rb;
        tile[kk][c] = Wout[(size_t)(k0 + kk) * Vv + n0 + c];
    }
    __syncthreads();
#pragma unroll
    for (int it = 0; it < 16; it++) {
        int nn = it * 4 + rb;
        BT[(size_t)(n0 + nn) * Hh + k0 + c] = __float2bfloat16(tile[c][nn]);
    }
}

// ---------------------------------------------------------------------------
// P4: pack the 4 recurrent matrices into bf16 [m][i/8][j][8] so the decoder's
// weight loads are 16B/lane dwordx4. m: 0=W1_top 1=Whz 2=Whr 3=Whh.
// ---------------------------------------------------------------------------
__global__ __launch_bounds__(256) void pack4_kernel(
    const float* __restrict__ W1, const float* __restrict__ Whz,
    const float* __restrict__ Whr, const float* __restrict__ Whh,
    __hip_bfloat16* __restrict__ PW)
{
    int c8 = blockIdx.x;           // i-chunk of 8 rows (0..31)
    int m  = blockIdx.y;           // matrix id
    int j  = threadIdx.x;          // column
    const float* src;
    switch (m) {
        case 0: src = W1;  break;  // top half (h part) = rows 0..H-1
        case 1: src = Whz; break;
        case 2: src = Whr; break;
        default: src = Whh; break;
    }
    __hip_bfloat16* dst = PW + (((size_t)m * 32 + c8) * Hh + j) * 8;
#pragma unroll
    for (int d = 0; d < 8; d++)
        dst[d] = __float2bfloat16(src[(c8 * 8 + d) * Hh + j]);
}

// ---------------------------------------------------------------------------
// K2: decoder scan. One block per batch element, 1024 threads. Per step only
// the 4 h-dependent matvecs stream from L2 (512 KB bf16, merged in one
// load-dense phase A); the 3 ctx matvecs are LDS table lookups (annZ/R/H),
// and ctx itself is never materialized. 6 barriers/step.
// ---------------------------------------------------------------------------
__global__ __launch_bounds__(1024) void decoder_kernel(
    const float* __restrict__ h0,
    const __hip_bfloat16* __restrict__ PW,
    const float* __restrict__ W2, const float* __restrict__ b2,
    const float* __restrict__ bhh,
    const __hip_bfloat16* __restrict__ annPb,
    const __hip_bfloat16* __restrict__ annZb,
    const __hip_bfloat16* __restrict__ annRb,
    const __hip_bfloat16* __restrict__ annHb,
    const float* __restrict__ eZ, const float* __restrict__ eR,
    const float* __restrict__ eH,
    __hip_bfloat16* __restrict__ hidBf, float* __restrict__ attOut)
{
    const int b = blockIdx.x, tid = threadIdx.x;
    const int j = tid & 255;       // output column
    const int q = tid >> 8;        // i-chunk / s-chunk (0..3)

    __shared__ unsigned short lZ[Ss * Hh];     // 32 KB  ctx-part tables (bf16)
    __shared__ unsigned short lR[Ss * Hh];     // 32 KB
    __shared__ unsigned short lHt[Ss * Hh];    // 32 KB
    __shared__ unsigned short lP[Ss][Hh + 2];  // 33 KB  annP, pitch 258 (bank-safe)
    __shared__ float sRed[16][Hh];             // 16 KB  partials (A then D')
    __shared__ float sLoc[4][Hh];              // 4 KB   reduced A streams
    __shared__ float sRedB[16][Ss];            // 4 KB   score partials
    __shared__ float awLoc[Ss];
    __shared__ __align__(16) float hLoc[Hh];
    __shared__ float w2Loc[Hh];

    // ---- preload (once per launch) ----
    {
        u16x8* dZ = (u16x8*)lZ;  const u16x8* sZ = (const u16x8*)(annZb + (size_t)b * Ss * Hh);
        u16x8* dR = (u16x8*)lR;  const u16x8* sR = (const u16x8*)(annRb + (size_t)b * Ss * Hh);
        u16x8* dH = (u16x8*)lHt; const u16x8* sHsrc = (const u16x8*)(annHb + (size_t)b * Ss * Hh);
        for (int idx = tid; idx < Ss * Hh / 8; idx += 1024) {
            dZ[idx] = sZ[idx]; dR[idx] = sR[idx]; dH[idx] = sHsrc[idx];
        }
        const unsigned short* sP = (const unsigned short*)(annPb + (size_t)b * Ss * Hh);
        for (int idx = tid; idx < Ss * Hh; idx += 1024)
            lP[idx >> 8][idx & 255] = sP[idx];
        if (tid < Hh) { hLoc[tid] = h0[b * Hh + tid]; w2Loc[tid] = W2[tid]; }
    }
    const float rbhh = (tid < Hh) ? bhh[j] : 0.f;
    const float b2s = b2[0];
    __syncthreads();

    const f32x4* h4 = (const f32x4*)hLoc;
    const u16x8* pw = (const u16x8*)PW;   // [m][c8][j] -> m*8192 + c8*256 + j

    for (int t = 0; t < Tt; t++) {
        const int rowt = b * Tt + t;

        // hoisted per-step embProj reads (latency hides under A)
        float ez = 0.f, er = 0.f, eh = 0.f;
        if (tid < Hh) {
            ez = eZ[(size_t)rowt * Hh + j];
            er = eR[(size_t)rowt * Hh + j];
            eh = eH[(size_t)rowt * Hh + j];
        }

        // --- A: all 4 recurrent matvecs in one pass (same h operand).
        // streams: 0=hProj(W1top) 1=Whz@h 2=Whr@h 3=Whh@h, 4-way i-split.
        {
            float hp = 0.f, hz = 0.f, hr = 0.f, hh = 0.f;
#pragma unroll 2
            for (int c = 0; c < 8; c++) {
                int c8 = q * 8 + c;
                int o = c8 * Hh + j;
                u16x8 w0 = pw[o], w1 = pw[8192 + o], w2v = pw[16384 + o], w3 = pw[24576 + o];
                f32x4 ha = h4[c8 * 2], hb = h4[c8 * 2 + 1];
#pragma unroll
                for (int d = 0; d < 4; d++) {
                    float x = ha[d];
                    hp = fmaf(bf2f(w0[d]), x, hp);
                    hz = fmaf(bf2f(w1[d]), x, hz);
                    hr = fmaf(bf2f(w2v[d]), x, hr);
                    hh = fmaf(bf2f(w3[d]), x, hh);
                }
#pragma unroll
                for (int d = 0; d < 4; d++) {
                    float x = hb[d];
                    hp = fmaf(bf2f(w0[d + 4]), x, hp);
                    hz = fmaf(bf2f(w1[d + 4]), x, hz);
                    hr = fmaf(bf2f(w2v[d + 4]), x, hr);
                    hh = fmaf(bf2f(w3[d + 4]), x, hh);
                }
            }
            sRed[q * 4 + 0][j] = hp;
            sRed[q * 4 + 1][j] = hz;
            sRed[q * 4 + 2][j] = hr;
            sRed[q * 4 + 3][j] = hh;
        }
        __syncthreads();

        // --- reduce the 4 streams: sLoc[st][j] (st: 0=hProj 1=hz 2=hr 3=hh)
        {
            int st = tid >> 8, jj = tid & 255;
            sLoc[st][jj] = sRed[st][jj] + sRed[4 + st][jj] +
                           sRed[8 + st][jj] + sRed[12 + st][jj];
        }
        __syncthreads();

        // --- B: u[s] partials, 16 j's per thread (g = 16 col-groups)
        {
            int s = tid & 63, g = tid >> 6;
            float pb = 0.f;
#pragma unroll
            for (int kk = 0; kk < 16; kk++) {
                int jj = g * 16 + kk;
                float v = sLoc[0][jj] + bf2f(lP[s][jj]);
                pb = fmaf(w2Loc[jj], fmaxf(v, 0.f), pb);
            }
            sRedB[g][s] = pb;
        }
        __syncthreads();

        // --- C: softmax over s (wave 0) + attentions write
        if (tid < 64) {
            float u = b2s;
#pragma unroll
            for (int g = 0; g < 16; g++) u += sRedB[g][tid];
            float m = u;
#pragma unroll
            for (int off = 32; off; off >>= 1) m = fmaxf(m, __shfl_xor(m, off));
            float e = __expf(u - m);
            float ssum = e;
#pragma unroll
            for (int off = 32; off; off >>= 1) ssum += __shfl_xor(ssum, off);
            float aw = e / ssum;
            awLoc[tid] = aw;
            attOut[((size_t)b * Ss + tid) * Tt + t] = aw;
        }
        __syncthreads();

        // --- D': gate input parts from LDS tables, 4-way s-split.
        // sum*[j] = sum_s aw[s] * ann*[s][j]  ==  Wi*_top @ ctx
        {
            float az = 0.f, ar = 0.f, ah = 0.f;
#pragma unroll
            for (int k2 = 0; k2 < 16; k2++) {
                int s = q * 16 + k2;
                float a = awLoc[s];
                int o = s * Hh + j;
                az = fmaf(a, bf2f(lZ[o]), az);
                ar = fmaf(a, bf2f(lR[o]), ar);
                ah = fmaf(a, bf2f(lHt[o]), ah);
            }
            sRed[q][j]     = az;   // rows 0..3
            sRed[4 + q][j] = ar;   // rows 4..7
            sRed[8 + q][j] = ah;   // rows 8..11
        }
        __syncthreads();

        // --- F: gate finalize + h update (threads 0..255)
        if (tid < Hh) {
            float sumZ = sRed[0][j] + sRed[1][j] + sRed[2][j] + sRed[3][j];
            float sumR = sRed[4][j] + sRed[5][j] + sRed[6][j] + sRed[7][j];
            float sumH = sRed[8][j] + sRed[9][j] + sRed[10][j] + sRed[11][j];
            float z = 1.f / (1.f + __expf(-(ez + sLoc[1][j] + sumZ)));
            float r = 1.f / (1.f + __expf(-(er + sLoc[2][j] + sumR)));
            float g = tanhf(eh + sumH + r * (sLoc[3][j] + rbhh));
            float hnew = (1.f - z) * g + z * hLoc[j];
            hLoc[j] = hnew;
            hidBf[(size_t)rowt * Hh + j] = __float2bfloat16(hnew);
        }
        __syncthreads();
    }
}

// ---------------------------------------------------------------------------
// K3: output = hiddens(bf16) @ WoutT^T(bf16) + bout, fp32 out.
// ---------------------------------------------------------------------------
__global__ __launch_bounds__(256) void out_gemm_kernel(
    const __hip_bfloat16* __restrict__ A,   // (2048,256)
    const __hip_bfloat16* __restrict__ BT,  // (32000,256)
    const float* __restrict__ bout,
    float* __restrict__ C)                  // (2048,32000)
{
    int n0 = blockIdx.x * 128, m0 = blockIdx.y * 128;
    int tid = threadIdx.x;
    int w = tid >> 6, l = tid & 63;
    int wm = (w >> 1) * 64, wn = (w & 1) * 64;
    int quad = l >> 4, l15 = l & 15;

    const __hip_bfloat16* Arow = A + (size_t)(m0 + wm + l15) * Hh + quad * 8;
    const __hip_bfloat16* Brow = BT + (size_t)(n0 + wn + l15) * Hh + quad * 8;

    f32x4 acc[4][4] = {};
#pragma unroll
    for (int kk = 0; kk < 8; kk++) {
        bf16x8 af[4], bfv[4];
#pragma unroll
        for (int mi = 0; mi < 4; mi++)
            af[mi] = *(const bf16x8*)(Arow + mi * 16 * Hh + kk * 32);
#pragma unroll
        for (int ni = 0; ni < 4; ni++)
            bfv[ni] = *(const bf16x8*)(Brow + ni * 16 * Hh + kk * 32);
#pragma unroll
        for (int mi = 0; mi < 4; mi++)
#pragma unroll
            for (int ni = 0; ni < 4; ni++)
                acc[mi][ni] = __builtin_amdgcn_mfma_f32_16x16x32_bf16(
                    af[mi], bfv[ni], acc[mi][ni], 0, 0, 0);
    }
#pragma unroll
    for (int ni = 0; ni < 4; ni++) {
        int col = n0 + wn + ni * 16 + l15;
        float bo = bout[col];
#pragma unroll
        for (int mi = 0; mi < 4; mi++) {
            int rowb = m0 + wm + mi * 16 + quad * 4;
#pragma unroll
            for (int r = 0; r < 4; r++)
                C[(size_t)(rowb + r) * Vv + col] = acc[mi][ni][r] + bo;
        }
    }
}

// ---------------------------------------------------------------------------
extern "C" void kernel_launch(void* const* d_in, const int* in_sizes, int n_in,
                              void* d_out, int out_size, void* d_ws, size_t ws_size,
                              hipStream_t stream) {
    const int*   toks = (const int*)d_in[0];
    const float* ann  = (const float*)d_in[1];
    const float* h0   = (const float*)d_in[2];
    const float* emb  = (const float*)d_in[3];
    const float* W1   = (const float*)d_in[4];
    const float* b1   = (const float*)d_in[5];
    const float* W2   = (const float*)d_in[6];
    const float* b2   = (const float*)d_in[7];
    const float* Wiz  = (const float*)d_in[8];
    const float* biz  = (const float*)d_in[9];
    const float* Wir  = (const float*)d_in[10];
    const float* bir  = (const float*)d_in[11];
    const float* Wih  = (const float*)d_in[12];
    const float* bih  = (const float*)d_in[13];
    const float* Whz  = (const float*)d_in[14];
    const float* bhz  = (const float*)d_in[15];
    const float* Whr  = (const float*)d_in[16];
    const float* bhr  = (const float*)d_in[17];
    const float* Whh  = (const float*)d_in[18];
    const float* bhh  = (const float*)d_in[19];
    const float* Wout = (const float*)d_in[20];
    const float* bout = (const float*)d_in[21];

    float* out    = (float*)d_out;
    float* attOut = out + (size_t)Bb * Tt * Vv;

    float* ws = (float*)d_ws;
    float* eZ = ws;                                            // 524288 f32
    float* eR = ws + 524288;
    float* eH = ws + 1048576;
    __hip_bfloat16* hidBf = (__hip_bfloat16*)(ws + 1572864);   // 524288 bf16
    __hip_bfloat16* WoutT = (__hip_bfloat16*)(ws + 1835008);   // 8192000 bf16
    __hip_bfloat16* annPb = (__hip_bfloat16*)(ws + 5931008);   // 524288 bf16
    __hip_bfloat16* annZb = (__hip_bfloat16*)(ws + 6193152);
    __hip_bfloat16* annRb = (__hip_bfloat16*)(ws + 6455296);
    __hip_bfloat16* annHb = (__hip_bfloat16*)(ws + 6717440);
    __hip_bfloat16* PW    = (__hip_bfloat16*)(ws + 6979584);   // 262144 bf16

    annprep_kernel<<<dim3(Bb * Ss / 8), dim3(256), 0, stream>>>(
        ann, W1, b1, Wiz, Wir, Wih, annPb, annZb, annRb, annHb);
    embproj_kernel<<<dim3(Bb * Tt / 4), dim3(256), 0, stream>>>(
        toks, emb, Wiz, Wir, Wih, biz, bir, bih, bhz, bhr, eZ, eR, eH);
    transpose_wout_kernel<<<dim3(Vv / 64, Hh / 64), dim3(256), 0, stream>>>(Wout, WoutT);
    pack4_kernel<<<dim3(32, 4), dim3(256), 0, stream>>>(W1, Whz, Whr, Whh, PW);
    decoder_kernel<<<dim3(Bb), dim3(1024), 0, stream>>>(
        h0, PW, W2, b2, bhh, annPb, annZb, annRb, annHb,
        eZ, eR, eH, hidBf, attOut);
    out_gemm_kernel<<<dim3(Vv / 128, (Bb * Tt) / 128), dim3(256), 0, stream>>>(
        hidBf, WoutT, bout, out);
}